// Round 1
// baseline (352.169 us; speedup 1.0000x reference)
//
#include <hip/hip_runtime.h>
#include <hip/hip_bf16.h>

#define B_ 2
#define T_ 1024
#define D_ 1024
#define H_ 8
#define DEPTH_ 5
#define DH_ 128

// -------------------------------------------------------------------------
// Kernel 1: paths = sigmoid(x @ Wp + bp), stored transposed (B,H,T,DEPTH).
// 4 rows of x per block; each wave handles 10 of the 40 outputs.
// -------------------------------------------------------------------------
__global__ __launch_bounds__(256) void paths_kernel(
    const float* __restrict__ x, const float* __restrict__ Wp,
    const float* __restrict__ bp, float* __restrict__ paths_t) {
  __shared__ float xs[4 * D_];  // 16 KB
  int row0 = blockIdx.x * 4;    // 4 rows per block, never crosses b boundary
  int tid = threadIdx.x;
  // load 4 contiguous rows (4096 floats) as float4
  for (int i = tid * 4; i < 4 * D_; i += 256 * 4) {
    *(float4*)&xs[i] = *(const float4*)&x[(size_t)row0 * D_ + i];
  }
  __syncthreads();
  int wave = tid >> 6;
  int lane = tid & 63;
  int b = row0 >> 10;
  int t0 = row0 & (T_ - 1);
  for (int oo = 0; oo < 10; ++oo) {
    int o = wave * 10 + oo;  // 0..39
    float s0 = 0.f, s1 = 0.f, s2 = 0.f, s3 = 0.f;
    for (int j = 0; j < D_ / 64; ++j) {
      int k = lane + j * 64;
      float wp = Wp[k * (H_ * DEPTH_) + o];
      s0 = fmaf(xs[0 * D_ + k], wp, s0);
      s1 = fmaf(xs[1 * D_ + k], wp, s1);
      s2 = fmaf(xs[2 * D_ + k], wp, s2);
      s3 = fmaf(xs[3 * D_ + k], wp, s3);
    }
#pragma unroll
    for (int off = 32; off >= 1; off >>= 1) {
      s0 += __shfl_down(s0, off, 64);
      s1 += __shfl_down(s1, off, 64);
      s2 += __shfl_down(s2, off, 64);
      s3 += __shfl_down(s3, off, 64);
    }
    if (lane == 0) {
      int h = o / DEPTH_, d = o % DEPTH_;
      float bias = bp[o];
      float z[4] = {s0 + bias, s1 + bias, s2 + bias, s3 + bias};
#pragma unroll
      for (int rr = 0; rr < 4; ++rr) {
        float p = 1.f / (1.f + __expf(-z[rr]));
        paths_t[(((size_t)(b * H_ + h) * T_ + t0 + rr) * DEPTH_) + d] = p;
      }
    }
  }
}

// -------------------------------------------------------------------------
// Kernel 2/4: C[MxN] = A[MxK] @ B[KxN], fp32, 64x64 tile, BK=16, 4x4/thread
// -------------------------------------------------------------------------
__global__ __launch_bounds__(256) void gemm_f32(
    const float* __restrict__ A, const float* __restrict__ Bmat,
    float* __restrict__ C, int M, int N, int K) {
  __shared__ float As[16][64];
  __shared__ float Bs[16][64];
  int tid = threadIdx.x;
  int tx = tid & 15;
  int ty = tid >> 4;
  int bm = blockIdx.y << 6;
  int bn = blockIdx.x << 6;
  float acc[4][4] = {};
  int lr = tid >> 2;          // 0..63  A tile row
  int lc = (tid & 3) << 2;    // 0,4,8,12  A tile k
  int kr = tid >> 4;          // 0..15  B tile k
  int nc = (tid & 15) << 2;   // B tile n
  const float* Aptr = A + (size_t)(bm + lr) * K + lc;
  const float* Bptr = Bmat + (size_t)kr * N + bn + nc;
  for (int k0 = 0; k0 < K; k0 += 16) {
    float4 a4 = *(const float4*)Aptr;
    float4 b4 = *(const float4*)Bptr;
    Aptr += 16;
    Bptr += (size_t)16 * N;
    As[lc + 0][lr] = a4.x;
    As[lc + 1][lr] = a4.y;
    As[lc + 2][lr] = a4.z;
    As[lc + 3][lr] = a4.w;
    *(float4*)&Bs[kr][nc] = b4;
    __syncthreads();
#pragma unroll
    for (int kk = 0; kk < 16; ++kk) {
      float4 av = *(const float4*)&As[kk][ty << 2];
      float4 bv = *(const float4*)&Bs[kk][tx << 2];
      float a[4] = {av.x, av.y, av.z, av.w};
      float bb[4] = {bv.x, bv.y, bv.z, bv.w};
#pragma unroll
      for (int i = 0; i < 4; ++i)
#pragma unroll
        for (int j = 0; j < 4; ++j) acc[i][j] = fmaf(a[i], bb[j], acc[i][j]);
    }
    __syncthreads();
  }
#pragma unroll
  for (int i = 0; i < 4; ++i) {
    float4 o = make_float4(acc[i][0], acc[i][1], acc[i][2], acc[i][3]);
    *(float4*)&C[(size_t)(bm + (ty << 2) + i) * N + bn + (tx << 2)] = o;
  }
}

// -------------------------------------------------------------------------
// Kernel 3: fused causal p-adic attention.
// grid = (T/32 q-tiles, B*H). block = 256 (4 waves, 8 q-rows per wave).
// sim in [0,1] -> softmax without max subtraction.
// -------------------------------------------------------------------------
#define QT 32
#define KT 64

__global__ __launch_bounds__(256) void attn_kernel(
    const float* __restrict__ paths_t, const float* __restrict__ V,
    float* __restrict__ ctx) {
  int bh = blockIdx.y;  // 0..15
  int b = bh >> 3;
  int h = bh & 7;
  int qt = gridDim.x - 1 - blockIdx.x;  // reversed: longest blocks first
  int q0 = qt * QT;
  int wave = threadIdx.x >> 6;
  int lane = threadIdx.x & 63;
  int r0 = wave * 8;

  __shared__ float Vs[KT][DH_];        // 32 KB
  __shared__ float Ps[KT][DEPTH_];     // 1.25 KB
  __shared__ float Qs[QT][DEPTH_];     // 0.625 KB
  __shared__ float Ws[4][8][KT];       // 8 KB

  const float* pb = paths_t + (size_t)bh * T_ * DEPTH_;
  // q-tile paths: contiguous QT*DEPTH floats
  for (int i = threadIdx.x; i < QT * DEPTH_; i += 256)
    ((float*)Qs)[i] = pb[q0 * DEPTH_ + i];

  float acc0[8] = {}, acc1[8] = {}, lsum[8] = {};

  int nkt = (q0 + QT - 1) / KT + 1;
  for (int kt = 0; kt < nkt; ++kt) {
    int k0 = kt * KT;
    __syncthreads();  // protect Vs/Ps from previous iteration's readers
    for (int i = threadIdx.x; i < KT * DEPTH_; i += 256)
      ((float*)Ps)[i] = pb[k0 * DEPTH_ + i];
    for (int i = threadIdx.x; i < KT * DH_ / 4; i += 256) {
      int idx = i * 4;
      int r = idx / DH_, c = idx & (DH_ - 1);
      *(float4*)&Vs[r][c] =
          *(const float4*)&V[(size_t)(b * T_ + k0 + r) * D_ + h * DH_ + c];
    }
    __syncthreads();

    // phase 1: lane computes w(q=r0+rr, k=lane) for its wave's 8 rows
    float pk[DEPTH_], mk[DEPTH_];
#pragma unroll
    for (int d = 0; d < DEPTH_; ++d) {
      pk[d] = Ps[lane][d];
      mk[d] = 1.f - pk[d];
    }
    int kg = k0 + lane;
#pragma unroll
    for (int rr = 0; rr < 8; ++rr) {
      int q = q0 + r0 + rr;
      float w = 0.f;
      if (kg <= q) {
        float cum = 1.f, s = 0.f;
#pragma unroll
        for (int d = 0; d < DEPTH_; ++d) {
          float pq = Qs[r0 + rr][d];
          float ag = fmaf(pq, pk[d], (1.f - pq) * mk[d]);
          cum *= ag;
          s += cum;
        }
        w = __expf(s * 0.2f);
      }
      Ws[wave][rr][lane] = w;
      lsum[rr] += w;
    }
    __syncthreads();

    // phase 2: acc += W @ V  (w read back as broadcast float4)
    for (int k4 = 0; k4 < KT; k4 += 4) {
      float v0[4], v1[4];
#pragma unroll
      for (int j = 0; j < 4; ++j) {
        v0[j] = Vs[k4 + j][lane];
        v1[j] = Vs[k4 + j][lane + 64];
      }
#pragma unroll
      for (int rr = 0; rr < 8; ++rr) {
        float4 w4 = *(const float4*)&Ws[wave][rr][k4];
        acc0[rr] = fmaf(w4.x, v0[0],
                   fmaf(w4.y, v0[1], fmaf(w4.z, v0[2], fmaf(w4.w, v0[3], acc0[rr]))));
        acc1[rr] = fmaf(w4.x, v1[0],
                   fmaf(w4.y, v1[1], fmaf(w4.z, v1[2], fmaf(w4.w, v1[3], acc1[rr]))));
      }
    }
  }

  // epilogue: normalize and write ctx (natural (B,T,D) layout)
#pragma unroll
  for (int rr = 0; rr < 8; ++rr) {
    float s = lsum[rr];
#pragma unroll
    for (int off = 32; off >= 1; off >>= 1) s += __shfl_xor(s, off, 64);
    float inv = 1.f / s;
    int q = q0 + r0 + rr;
    float* crow = ctx + (size_t)(b * T_ + q) * D_ + h * DH_;
    crow[lane] = acc0[rr] * inv;
    crow[lane + 64] = acc1[rr] * inv;
  }
}

// -------------------------------------------------------------------------
extern "C" void kernel_launch(void* const* d_in, const int* in_sizes, int n_in,
                              void* d_out, int out_size, void* d_ws,
                              size_t ws_size, hipStream_t stream) {
  const float* x = (const float*)d_in[0];
  const float* Wp = (const float*)d_in[1];
  const float* bp = (const float*)d_in[2];
  const float* Wv = (const float*)d_in[3];
  const float* Wo = (const float*)d_in[4];
  float* out = (float*)d_out;

  float* wsf = (float*)d_ws;
  float* paths_t = wsf;                          // B*H*T*DEPTH = 81920 floats
  float* V = wsf + 81920;                        // B*T*D = 2M floats
  float* ctx = V + (size_t)B_ * T_ * D_;         // 2M floats

  paths_kernel<<<dim3(B_ * T_ / 4), 256, 0, stream>>>(x, Wp, bp, paths_t);
  gemm_f32<<<dim3(D_ / 64, B_ * T_ / 64), 256, 0, stream>>>(x, Wv, V,
                                                            B_ * T_, D_, D_);
  attn_kernel<<<dim3(T_ / QT, B_ * H_), 256, 0, stream>>>(paths_t, V, ctx);
  gemm_f32<<<dim3(D_ / 64, B_ * T_ / 64), 256, 0, stream>>>(ctx, Wo, out,
                                                            B_ * T_, D_, D_);
}

// Round 2
// 268.416 us; speedup vs baseline: 1.3120x; 1.3120x over previous
//
#include <hip/hip_runtime.h>
#include <hip/hip_bf16.h>

#define B_ 2
#define T_ 1024
#define D_ 1024
#define H_ 8
#define DEPTH_ 5
#define DH_ 128

typedef short s16x8 __attribute__((ext_vector_type(8)));
typedef float f32x4 __attribute__((ext_vector_type(4)));

__device__ inline short f2bf(float f) {
  __hip_bfloat16 h = __float2bfloat16(f);
  return *reinterpret_cast<short*>(&h);
}

// -------------------------------------------------------------------------
// Kernel 1: paths = sigmoid(x @ Wp + bp), stored transposed (B,H,T,DEPTH).
// -------------------------------------------------------------------------
__global__ __launch_bounds__(256) void paths_kernel(
    const float* __restrict__ x, const float* __restrict__ Wp,
    const float* __restrict__ bp, float* __restrict__ paths_t) {
  __shared__ float xs[4 * D_];  // 16 KB
  int row0 = blockIdx.x * 4;
  int tid = threadIdx.x;
  for (int i = tid * 4; i < 4 * D_; i += 256 * 4) {
    *(float4*)&xs[i] = *(const float4*)&x[(size_t)row0 * D_ + i];
  }
  __syncthreads();
  int wave = tid >> 6;
  int lane = tid & 63;
  int b = row0 >> 10;
  int t0 = row0 & (T_ - 1);
  for (int oo = 0; oo < 10; ++oo) {
    int o = wave * 10 + oo;  // 0..39
    float s0 = 0.f, s1 = 0.f, s2 = 0.f, s3 = 0.f;
    for (int j = 0; j < D_ / 64; ++j) {
      int k = lane + j * 64;
      float wp = Wp[k * (H_ * DEPTH_) + o];
      s0 = fmaf(xs[0 * D_ + k], wp, s0);
      s1 = fmaf(xs[1 * D_ + k], wp, s1);
      s2 = fmaf(xs[2 * D_ + k], wp, s2);
      s3 = fmaf(xs[3 * D_ + k], wp, s3);
    }
#pragma unroll
    for (int off = 32; off >= 1; off >>= 1) {
      s0 += __shfl_down(s0, off, 64);
      s1 += __shfl_down(s1, off, 64);
      s2 += __shfl_down(s2, off, 64);
      s3 += __shfl_down(s3, off, 64);
    }
    if (lane == 0) {
      int h = o / DEPTH_, d = o % DEPTH_;
      float bias = bp[o];
      float z[4] = {s0 + bias, s1 + bias, s2 + bias, s3 + bias};
#pragma unroll
      for (int rr = 0; rr < 4; ++rr) {
        float p = 1.f / (1.f + __expf(-z[rr]));
        paths_t[(((size_t)(b * H_ + h) * T_ + t0 + rr) * DEPTH_) + d] = p;
      }
    }
  }
}

// -------------------------------------------------------------------------
// Transpose + fp32->bf16 convert: W[K][N] -> Wt[N][K] (bf16, k contiguous)
// 64x64 tiles, 256 threads.
// -------------------------------------------------------------------------
__global__ __launch_bounds__(256) void transpose_convert(
    const float* __restrict__ W, short* __restrict__ Wt, int K, int N) {
  __shared__ float tile[64][65];
  int k0 = blockIdx.y * 64, n0 = blockIdx.x * 64;
  int tid = threadIdx.x;
#pragma unroll
  for (int i = 0; i < 4; ++i) {
    int idx = tid + i * 256;  // 0..1023
    int r = idx >> 4, c4 = (idx & 15) * 4;
    float4 v = *(const float4*)&W[(size_t)(k0 + r) * N + n0 + c4];
    tile[r][c4 + 0] = v.x;
    tile[r][c4 + 1] = v.y;
    tile[r][c4 + 2] = v.z;
    tile[r][c4 + 3] = v.w;
  }
  __syncthreads();
#pragma unroll
  for (int j = 0; j < 2; ++j) {
    int idx = tid + j * 256;  // 0..511
    int n = idx >> 3, k8 = (idx & 7) * 8;
    s16x8 outv;
#pragma unroll
    for (int jj = 0; jj < 8; ++jj) outv[jj] = f2bf(tile[k8 + jj][n]);
    *(s16x8*)&Wt[(size_t)(n0 + n) * K + k0 + k8] = outv;
  }
}

// -------------------------------------------------------------------------
// MFMA bf16 GEMM: C[M][N] = A[M][K] @ B, with B given pre-transposed
// bf16 Bt[N][K]. A is fp32 (converted during staging) or bf16.
// 64x64 block tile, BK=32, 4 waves (2x2), wave tile 32x32 (2x2 MFMA tiles).
// mfma_f32_16x16x32_bf16; C/D: col=lane&15, row=(lane>>4)*4+reg.
// -------------------------------------------------------------------------
template <bool A_IS_BF16>
__global__ __launch_bounds__(256) void gemm_bf16(
    const void* __restrict__ A_, const short* __restrict__ Bt,
    float* __restrict__ C, int M, int N, int K) {
  __shared__ short As[64 * 32];
  __shared__ short Bs[64 * 32];
  int tid = threadIdx.x;
  int bm = blockIdx.y << 6, bn = blockIdx.x << 6;
  int wave = tid >> 6, lane = tid & 63;
  int wm = (wave >> 1) * 32, wn = (wave & 1) * 32;
  int srow = tid >> 2, skoff = (tid & 3) * 8;  // staging: row 0..63, k-chunk
  f32x4 acc[2][2] = {{{0.f, 0.f, 0.f, 0.f}, {0.f, 0.f, 0.f, 0.f}},
                     {{0.f, 0.f, 0.f, 0.f}, {0.f, 0.f, 0.f, 0.f}}};

  const float* Af = (const float*)A_;
  const short* Ab = (const short*)A_;
  int fr = lane & 15, fq = (lane >> 4) * 8;

  for (int k0 = 0; k0 < K; k0 += 32) {
    s16x8 aval;
    if (A_IS_BF16) {
      aval = *(const s16x8*)&Ab[(size_t)(bm + srow) * K + k0 + skoff];
    } else {
      const float* p = &Af[(size_t)(bm + srow) * K + k0 + skoff];
      float4 f0 = *(const float4*)p;
      float4 f1 = *(const float4*)(p + 4);
      aval[0] = f2bf(f0.x); aval[1] = f2bf(f0.y);
      aval[2] = f2bf(f0.z); aval[3] = f2bf(f0.w);
      aval[4] = f2bf(f1.x); aval[5] = f2bf(f1.y);
      aval[6] = f2bf(f1.z); aval[7] = f2bf(f1.w);
    }
    s16x8 bval = *(const s16x8*)&Bt[(size_t)(bn + srow) * K + k0 + skoff];
    __syncthreads();  // previous iteration's fragment readers done
    *(s16x8*)&As[srow * 32 + skoff] = aval;
    *(s16x8*)&Bs[srow * 32 + skoff] = bval;
    __syncthreads();
    s16x8 af[2], bf[2];
    af[0] = *(const s16x8*)&As[(wm + fr) * 32 + fq];
    af[1] = *(const s16x8*)&As[(wm + 16 + fr) * 32 + fq];
    bf[0] = *(const s16x8*)&Bs[(wn + fr) * 32 + fq];
    bf[1] = *(const s16x8*)&Bs[(wn + 16 + fr) * 32 + fq];
#pragma unroll
    for (int mi = 0; mi < 2; ++mi)
#pragma unroll
      for (int ni = 0; ni < 2; ++ni)
        acc[mi][ni] = __builtin_amdgcn_mfma_f32_16x16x32_bf16(
            af[mi], bf[ni], acc[mi][ni], 0, 0, 0);
  }
  int col = lane & 15, rbase = (lane >> 4) * 4;
#pragma unroll
  for (int mi = 0; mi < 2; ++mi)
#pragma unroll
    for (int ni = 0; ni < 2; ++ni)
#pragma unroll
      for (int r = 0; r < 4; ++r)
        C[(size_t)(bm + wm + mi * 16 + rbase + r) * N + bn + wn + ni * 16 +
          col] = acc[mi][ni][r];
}

// -------------------------------------------------------------------------
// Kernel 3: fused causal p-adic attention (unchanged except bf16 ctx write).
// -------------------------------------------------------------------------
#define QT 32
#define KT 64

__global__ __launch_bounds__(256) void attn_kernel(
    const float* __restrict__ paths_t, const float* __restrict__ V,
    short* __restrict__ ctxb) {
  int bh = blockIdx.y;  // 0..15
  int b = bh >> 3;
  int h = bh & 7;
  int qt = gridDim.x - 1 - blockIdx.x;  // reversed: longest blocks first
  int q0 = qt * QT;
  int wave = threadIdx.x >> 6;
  int lane = threadIdx.x & 63;
  int r0 = wave * 8;

  __shared__ float Vs[KT][DH_];     // 32 KB
  __shared__ float Ps[KT][DEPTH_];  // 1.25 KB
  __shared__ float Qs[QT][DEPTH_];  // 0.625 KB
  __shared__ float Ws[4][8][KT];    // 8 KB

  const float* pb = paths_t + (size_t)bh * T_ * DEPTH_;
  for (int i = threadIdx.x; i < QT * DEPTH_; i += 256)
    ((float*)Qs)[i] = pb[q0 * DEPTH_ + i];

  float acc0[8] = {}, acc1[8] = {}, lsum[8] = {};

  int nkt = (q0 + QT - 1) / KT + 1;
  for (int kt = 0; kt < nkt; ++kt) {
    int k0 = kt * KT;
    __syncthreads();
    for (int i = threadIdx.x; i < KT * DEPTH_; i += 256)
      ((float*)Ps)[i] = pb[k0 * DEPTH_ + i];
    for (int i = threadIdx.x; i < KT * DH_ / 4; i += 256) {
      int idx = i * 4;
      int r = idx / DH_, c = idx & (DH_ - 1);
      *(float4*)&Vs[r][c] =
          *(const float4*)&V[(size_t)(b * T_ + k0 + r) * D_ + h * DH_ + c];
    }
    __syncthreads();

    float pk[DEPTH_], mk[DEPTH_];
#pragma unroll
    for (int d = 0; d < DEPTH_; ++d) {
      pk[d] = Ps[lane][d];
      mk[d] = 1.f - pk[d];
    }
    int kg = k0 + lane;
#pragma unroll
    for (int rr = 0; rr < 8; ++rr) {
      int q = q0 + r0 + rr;
      float w = 0.f;
      if (kg <= q) {
        float cum = 1.f, s = 0.f;
#pragma unroll
        for (int d = 0; d < DEPTH_; ++d) {
          float pq = Qs[r0 + rr][d];
          float ag = fmaf(pq, pk[d], (1.f - pq) * mk[d]);
          cum *= ag;
          s += cum;
        }
        w = __expf(s * 0.2f);
      }
      Ws[wave][rr][lane] = w;
      lsum[rr] += w;
    }
    __syncthreads();

    for (int k4 = 0; k4 < KT; k4 += 4) {
      float v0[4], v1[4];
#pragma unroll
      for (int j = 0; j < 4; ++j) {
        v0[j] = Vs[k4 + j][lane];
        v1[j] = Vs[k4 + j][lane + 64];
      }
#pragma unroll
      for (int rr = 0; rr < 8; ++rr) {
        float4 w4 = *(const float4*)&Ws[wave][rr][k4];
        acc0[rr] = fmaf(w4.x, v0[0],
                   fmaf(w4.y, v0[1], fmaf(w4.z, v0[2], fmaf(w4.w, v0[3], acc0[rr]))));
        acc1[rr] = fmaf(w4.x, v1[0],
                   fmaf(w4.y, v1[1], fmaf(w4.z, v1[2], fmaf(w4.w, v1[3], acc1[rr]))));
      }
    }
  }

#pragma unroll
  for (int rr = 0; rr < 8; ++rr) {
    float s = lsum[rr];
#pragma unroll
    for (int off = 32; off >= 1; off >>= 1) s += __shfl_xor(s, off, 64);
    float inv = 1.f / s;
    int q = q0 + r0 + rr;
    short* crow = ctxb + (size_t)(b * T_ + q) * D_ + h * DH_;
    crow[lane] = f2bf(acc0[rr] * inv);
    crow[lane + 64] = f2bf(acc1[rr] * inv);
  }
}

// -------------------------------------------------------------------------
extern "C" void kernel_launch(void* const* d_in, const int* in_sizes, int n_in,
                              void* d_out, int out_size, void* d_ws,
                              size_t ws_size, hipStream_t stream) {
  const float* x = (const float*)d_in[0];
  const float* Wp = (const float*)d_in[1];
  const float* bp = (const float*)d_in[2];
  const float* Wv = (const float*)d_in[3];
  const float* Wo = (const float*)d_in[4];
  float* out = (float*)d_out;

  char* ws = (char*)d_ws;
  float* paths_t = (float*)ws;                   //  327,680 B
  float* V = (float*)(ws + 327680);              // 8,388,608 B
  short* Wvt = (short*)(ws + 327680 + 8388608);  // 2,097,152 B
  short* Wot = (short*)(ws + 327680 + 8388608 + 2097152);
  short* ctxb = (short*)(ws + 327680 + 8388608 + 2 * 2097152);  // 4 MB
  // total 17,104,896 B — same footprint as the proven round-1 layout

  transpose_convert<<<dim3(16, 16), 256, 0, stream>>>(Wv, Wvt, D_, D_);
  transpose_convert<<<dim3(16, 16), 256, 0, stream>>>(Wo, Wot, D_, D_);
  paths_kernel<<<dim3(B_ * T_ / 4), 256, 0, stream>>>(x, Wp, bp, paths_t);
  gemm_bf16<false><<<dim3(D_ / 64, B_ * T_ / 64), 256, 0, stream>>>(
      (const void*)x, Wvt, V, B_ * T_, D_, D_);
  attn_kernel<<<dim3(T_ / QT, B_ * H_), 256, 0, stream>>>(paths_t, V, ctxb);
  gemm_bf16<true><<<dim3(D_ / 64, B_ * T_ / 64), 256, 0, stream>>>(
      (const void*)ctxb, Wot, out, B_ * T_, D_, D_);
}

// Round 3
// 179.259 us; speedup vs baseline: 1.9646x; 1.4974x over previous
//
#include <hip/hip_runtime.h>
#include <hip/hip_bf16.h>

#define B_ 2
#define T_ 1024
#define D_ 1024
#define H_ 8
#define DEPTH_ 5
#define DH_ 128

typedef short s16x8 __attribute__((ext_vector_type(8)));
typedef short s16x4 __attribute__((ext_vector_type(4)));
typedef float f32x4 __attribute__((ext_vector_type(4)));

__device__ inline short f2bf(float f) {
  __hip_bfloat16 h = __float2bfloat16(f);
  return *reinterpret_cast<short*>(&h);
}

// -------------------------------------------------------------------------
// Kernel 1: paths = sigmoid(x @ Wp + bp), stored transposed (B,H,T,DEPTH).
// -------------------------------------------------------------------------
__global__ __launch_bounds__(256) void paths_kernel(
    const float* __restrict__ x, const float* __restrict__ Wp,
    const float* __restrict__ bp, float* __restrict__ paths_t) {
  __shared__ float xs[4 * D_];  // 16 KB
  int row0 = blockIdx.x * 4;
  int tid = threadIdx.x;
  for (int i = tid * 4; i < 4 * D_; i += 256 * 4) {
    *(float4*)&xs[i] = *(const float4*)&x[(size_t)row0 * D_ + i];
  }
  __syncthreads();
  int wave = tid >> 6;
  int lane = tid & 63;
  int b = row0 >> 10;
  int t0 = row0 & (T_ - 1);
  for (int oo = 0; oo < 10; ++oo) {
    int o = wave * 10 + oo;  // 0..39
    float s0 = 0.f, s1 = 0.f, s2 = 0.f, s3 = 0.f;
    for (int j = 0; j < D_ / 64; ++j) {
      int k = lane + j * 64;
      float wp = Wp[k * (H_ * DEPTH_) + o];
      s0 = fmaf(xs[0 * D_ + k], wp, s0);
      s1 = fmaf(xs[1 * D_ + k], wp, s1);
      s2 = fmaf(xs[2 * D_ + k], wp, s2);
      s3 = fmaf(xs[3 * D_ + k], wp, s3);
    }
#pragma unroll
    for (int off = 32; off >= 1; off >>= 1) {
      s0 += __shfl_down(s0, off, 64);
      s1 += __shfl_down(s1, off, 64);
      s2 += __shfl_down(s2, off, 64);
      s3 += __shfl_down(s3, off, 64);
    }
    if (lane == 0) {
      int h = o / DEPTH_, d = o % DEPTH_;
      float bias = bp[o];
      float z[4] = {s0 + bias, s1 + bias, s2 + bias, s3 + bias};
#pragma unroll
      for (int rr = 0; rr < 4; ++rr) {
        float p = 1.f / (1.f + __expf(-z[rr]));
        paths_t[(((size_t)(b * H_ + h) * T_ + t0 + rr) * DEPTH_) + d] = p;
      }
    }
  }
}

// -------------------------------------------------------------------------
// Transpose + fp32->bf16 convert: W[K][N] -> Wt[N][K] (bf16, k contiguous)
// -------------------------------------------------------------------------
__global__ __launch_bounds__(256) void transpose_convert(
    const float* __restrict__ W, short* __restrict__ Wt, int K, int N) {
  __shared__ float tile[64][65];
  int k0 = blockIdx.y * 64, n0 = blockIdx.x * 64;
  int tid = threadIdx.x;
#pragma unroll
  for (int i = 0; i < 4; ++i) {
    int idx = tid + i * 256;  // 0..1023
    int r = idx >> 4, c4 = (idx & 15) * 4;
    float4 v = *(const float4*)&W[(size_t)(k0 + r) * N + n0 + c4];
    tile[r][c4 + 0] = v.x;
    tile[r][c4 + 1] = v.y;
    tile[r][c4 + 2] = v.z;
    tile[r][c4 + 3] = v.w;
  }
  __syncthreads();
#pragma unroll
  for (int j = 0; j < 2; ++j) {
    int idx = tid + j * 256;  // 0..511
    int n = idx >> 3, k8 = (idx & 7) * 8;
    s16x8 outv;
#pragma unroll
    for (int jj = 0; jj < 8; ++jj) outv[jj] = f2bf(tile[k8 + jj][n]);
    *(s16x8*)&Wt[(size_t)(n0 + n) * K + k0 + k8] = outv;
  }
}

// -------------------------------------------------------------------------
// MFMA bf16 GEMM: C = A[M][K] @ B with Bt[N][K] bf16 pre-transposed.
// 64x64 block tile, BK=64, padded LDS (stride 72), 4 waves, 2x2 MFMA/wave.
// OUT_VT: write bf16 V transposed as Vt[(b*8+h)][dh][t] (for attention).
// -------------------------------------------------------------------------
#define LS 72
template <bool A_IS_BF16, bool OUT_VT>
__global__ __launch_bounds__(256) void gemm_bf16(
    const void* __restrict__ A_, const short* __restrict__ Bt, void* C_,
    int M, int N, int K) {
  __shared__ short As[64 * LS];
  __shared__ short Bs[64 * LS];
  int tid = threadIdx.x;
  int bm = blockIdx.y << 6, bn = blockIdx.x << 6;
  int wave = tid >> 6, lane = tid & 63;
  int wm = (wave >> 1) * 32, wn = (wave & 1) * 32;
  f32x4 acc[2][2] = {{{0.f, 0.f, 0.f, 0.f}, {0.f, 0.f, 0.f, 0.f}},
                     {{0.f, 0.f, 0.f, 0.f}, {0.f, 0.f, 0.f, 0.f}}};
  const float* Af = (const float*)A_;
  const short* Ab = (const short*)A_;

  for (int k0 = 0; k0 < K; k0 += 64) {
    s16x8 av[2], bv[2];
#pragma unroll
    for (int i = 0; i < 2; ++i) {
      int c = tid + i * 256;
      int row = c >> 3, ko = (c & 7) * 8;
      if (A_IS_BF16) {
        av[i] = *(const s16x8*)&Ab[(size_t)(bm + row) * K + k0 + ko];
      } else {
        const float* p = &Af[(size_t)(bm + row) * K + k0 + ko];
        float4 f0 = *(const float4*)p;
        float4 f1 = *(const float4*)(p + 4);
        av[i][0] = f2bf(f0.x); av[i][1] = f2bf(f0.y);
        av[i][2] = f2bf(f0.z); av[i][3] = f2bf(f0.w);
        av[i][4] = f2bf(f1.x); av[i][5] = f2bf(f1.y);
        av[i][6] = f2bf(f1.z); av[i][7] = f2bf(f1.w);
      }
      bv[i] = *(const s16x8*)&Bt[(size_t)(bn + row) * K + k0 + ko];
    }
    __syncthreads();  // previous iteration's fragment readers done
#pragma unroll
    for (int i = 0; i < 2; ++i) {
      int c = tid + i * 256;
      int row = c >> 3, ko = (c & 7) * 8;
      *(s16x8*)&As[row * LS + ko] = av[i];
      *(s16x8*)&Bs[row * LS + ko] = bv[i];
    }
    __syncthreads();
#pragma unroll
    for (int ks = 0; ks < 2; ++ks) {
      int ko = ks * 32 + (lane >> 4) * 8;
      int fr = lane & 15;
      s16x8 a0 = *(const s16x8*)&As[(wm + fr) * LS + ko];
      s16x8 a1 = *(const s16x8*)&As[(wm + 16 + fr) * LS + ko];
      s16x8 b0 = *(const s16x8*)&Bs[(wn + fr) * LS + ko];
      s16x8 b1 = *(const s16x8*)&Bs[(wn + 16 + fr) * LS + ko];
      acc[0][0] = __builtin_amdgcn_mfma_f32_16x16x32_bf16(a0, b0, acc[0][0], 0, 0, 0);
      acc[0][1] = __builtin_amdgcn_mfma_f32_16x16x32_bf16(a0, b1, acc[0][1], 0, 0, 0);
      acc[1][0] = __builtin_amdgcn_mfma_f32_16x16x32_bf16(a1, b0, acc[1][0], 0, 0, 0);
      acc[1][1] = __builtin_amdgcn_mfma_f32_16x16x32_bf16(a1, b1, acc[1][1], 0, 0, 0);
    }
  }
  int col = lane & 15, rbase = (lane >> 4) * 4;
  if (OUT_VT) {
    short* Vt = (short*)C_;
#pragma unroll
    for (int mi = 0; mi < 2; ++mi)
#pragma unroll
      for (int ni = 0; ni < 2; ++ni) {
        int m = bm + wm + mi * 16 + rbase;       // t start (4 consecutive)
        int n = bn + wn + ni * 16 + col;         // full dh col
        int b = m >> 10, t = m & (T_ - 1);
        int h = n >> 7, dh = n & (DH_ - 1);
        s16x4 v4;
#pragma unroll
        for (int r = 0; r < 4; ++r) v4[r] = f2bf(acc[mi][ni][r]);
        *(s16x4*)&Vt[((size_t)((b * H_ + h) * DH_ + dh)) * T_ + t] = v4;
      }
  } else {
    float* C = (float*)C_;
#pragma unroll
    for (int mi = 0; mi < 2; ++mi)
#pragma unroll
      for (int ni = 0; ni < 2; ++ni)
#pragma unroll
        for (int r = 0; r < 4; ++r)
          C[(size_t)(bm + wm + mi * 16 + rbase + r) * N + bn + wn + ni * 16 +
            col] = acc[mi][ni][r];
  }
}

// -------------------------------------------------------------------------
// Kernel 3: fused causal p-adic attention, MFMA P·V.
// grid (16, B*H). Block handles q-tile pair (bx, 31-bx): exactly 17 k-tiles.
// Sim: thread = one k-column (k=k0+lane), 8 q-rows (wave*8+j); pq/mq in regs.
// S -> LDS bf16 (A-frag layout), Vt tile -> LDS [dh][k] bf16 (B-frag layout).
// sim in [0,1] -> no max tracking; w = exp(sim/5), normalize at end.
// -------------------------------------------------------------------------
#define QT 32
#define KT 64

__global__ __launch_bounds__(256) void attn_kernel(
    const float* __restrict__ paths_t, const short* __restrict__ Vt,
    short* __restrict__ ctxb) {
  int bh = blockIdx.y;  // 0..15
  int b = bh >> 3, h = bh & 7;
  int bx = blockIdx.x;  // 0..15
  int wave = threadIdx.x >> 6, lane = threadIdx.x & 63;

  __shared__ short Vs[DH_ * LS];  // 18432 B  [dh][k], stride 72
  __shared__ short Ss[QT * LS];   //  4608 B  [q][k],  stride 72
  __shared__ float lsum_s[QT];

  const float* pb = paths_t + (size_t)bh * T_ * DEPTH_;
  const short* vb = Vt + (size_t)bh * DH_ * T_;

  for (int half = 0; half < 2; ++half) {
    int qt = half ? (31 - bx) : bx;
    int q0 = qt * QT;
    int nkt = (q0 + QT - 1) / KT + 1;  // pair total = 17 always

    // hoist this wave's 8 q-row path probs into registers
    float pq[8][DEPTH_], mq[8][DEPTH_];
#pragma unroll
    for (int j = 0; j < 8; ++j) {
      const float* qr = pb + (size_t)(q0 + wave * 8 + j) * DEPTH_;
#pragma unroll
      for (int d = 0; d < DEPTH_; ++d) {
        pq[j][d] = qr[d];
        mq[j][d] = 1.f - pq[j][d];
      }
    }
    f32x4 acc[2][2] = {{{0.f, 0.f, 0.f, 0.f}, {0.f, 0.f, 0.f, 0.f}},
                       {{0.f, 0.f, 0.f, 0.f}, {0.f, 0.f, 0.f, 0.f}}};
    float part[8] = {};

    for (int kt = 0; kt < nkt; ++kt) {
      int k0 = kt * KT;
      __syncthreads();  // prev MFMA readers / epilogue done
      // stage V tile: 128 dh rows x 64 k, bf16
#pragma unroll
      for (int i = 0; i < 4; ++i) {
        int c = threadIdx.x + i * 256;
        int dh = c >> 3, ko = (c & 7) * 8;
        *(s16x8*)&Vs[dh * LS + ko] =
            *(const s16x8*)&vb[(size_t)dh * T_ + k0 + ko];
      }
      // sim for k = k0+lane, q rows q0 + wave*8 + j
      int kg = k0 + lane;
      const float* kr = pb + (size_t)kg * DEPTH_;
      float pk[DEPTH_], mk[DEPTH_];
#pragma unroll
      for (int d = 0; d < DEPTH_; ++d) {
        pk[d] = kr[d];
        mk[d] = 1.f - pk[d];
      }
#pragma unroll
      for (int j = 0; j < 8; ++j) {
        int qg = q0 + wave * 8 + j;
        float a0 = fmaf(pq[j][0], pk[0], mq[j][0] * mk[0]);
        float a1 = fmaf(pq[j][1], pk[1], mq[j][1] * mk[1]);
        float a2 = fmaf(pq[j][2], pk[2], mq[j][2] * mk[2]);
        float a3 = fmaf(pq[j][3], pk[3], mq[j][3] * mk[3]);
        float a4 = fmaf(pq[j][4], pk[4], mq[j][4] * mk[4]);
        float t4 = 1.f + a4;
        float t3 = fmaf(a3, t4, 1.f);
        float t2 = fmaf(a2, t3, 1.f);
        float t1 = fmaf(a1, t2, 1.f);
        float s = a0 * t1;  // = sum of cumprods
        float w = (kg <= qg) ? __expf(s * 0.2f) : 0.f;
        part[j] += w;
        Ss[(wave * 8 + j) * LS + lane] = f2bf(w);
      }
      __syncthreads();
      // P @ V via MFMA: wave covers dh [32*wave, 32*wave+32)
#pragma unroll
      for (int ks = 0; ks < 2; ++ks) {
        int ko = ks * 32 + (lane >> 4) * 8;
        int fr = lane & 15;
        s16x8 sa0 = *(const s16x8*)&Ss[fr * LS + ko];
        s16x8 sa1 = *(const s16x8*)&Ss[(16 + fr) * LS + ko];
        s16x8 vb0 = *(const s16x8*)&Vs[(wave * 32 + fr) * LS + ko];
        s16x8 vb1 = *(const s16x8*)&Vs[(wave * 32 + 16 + fr) * LS + ko];
        acc[0][0] = __builtin_amdgcn_mfma_f32_16x16x32_bf16(sa0, vb0, acc[0][0], 0, 0, 0);
        acc[0][1] = __builtin_amdgcn_mfma_f32_16x16x32_bf16(sa0, vb1, acc[0][1], 0, 0, 0);
        acc[1][0] = __builtin_amdgcn_mfma_f32_16x16x32_bf16(sa1, vb0, acc[1][0], 0, 0, 0);
        acc[1][1] = __builtin_amdgcn_mfma_f32_16x16x32_bf16(sa1, vb1, acc[1][1], 0, 0, 0);
      }
    }
    // reduce per-q row sums across the wave's 64 k-lanes
#pragma unroll
    for (int j = 0; j < 8; ++j) {
      float s = part[j];
#pragma unroll
      for (int off = 32; off >= 1; off >>= 1) s += __shfl_xor(s, off, 64);
      if (lane == j) lsum_s[wave * 8 + j] = s;
    }
    __syncthreads();
    // epilogue: normalize, write bf16 ctx
    int col = lane & 15, rbase = (lane >> 4) * 4;
#pragma unroll
    for (int qt2 = 0; qt2 < 2; ++qt2)
#pragma unroll
      for (int ni = 0; ni < 2; ++ni)
#pragma unroll
        for (int r = 0; r < 4; ++r) {
          int ql = qt2 * 16 + rbase + r;
          int dh = wave * 32 + ni * 16 + col;
          float val = acc[qt2][ni][r] / lsum_s[ql];
          ctxb[(size_t)(b * T_ + q0 + ql) * D_ + h * DH_ + dh] = f2bf(val);
        }
  }
}

// -------------------------------------------------------------------------
extern "C" void kernel_launch(void* const* d_in, const int* in_sizes, int n_in,
                              void* d_out, int out_size, void* d_ws,
                              size_t ws_size, hipStream_t stream) {
  const float* x = (const float*)d_in[0];
  const float* Wp = (const float*)d_in[1];
  const float* bp = (const float*)d_in[2];
  const float* Wv = (const float*)d_in[3];
  const float* Wo = (const float*)d_in[4];
  float* out = (float*)d_out;

  char* ws = (char*)d_ws;
  float* paths_t = (float*)ws;                       //   327,680 B
  short* Vt = (short*)(ws + 327680);                 // 4,194,304 B (bf16, [bh][dh][t])
  short* Wvt = (short*)(ws + 327680 + 4194304);      // 2,097,152 B
  short* Wot = (short*)(ws + 327680 + 4194304 + 2097152);
  short* ctxb = (short*)(ws + 327680 + 4194304 + 2 * 2097152);  // 4 MB
  // total ~12.9 MB (fits the proven 17.1 MB footprint)

  transpose_convert<<<dim3(16, 16), 256, 0, stream>>>(Wv, Wvt, D_, D_);
  transpose_convert<<<dim3(16, 16), 256, 0, stream>>>(Wo, Wot, D_, D_);
  paths_kernel<<<dim3(B_ * T_ / 4), 256, 0, stream>>>(x, Wp, bp, paths_t);
  gemm_bf16<false, true><<<dim3(D_ / 64, B_ * T_ / 64), 256, 0, stream>>>(
      (const void*)x, Wvt, (void*)Vt, B_ * T_, D_, D_);
  attn_kernel<<<dim3(16, B_ * H_), 256, 0, stream>>>(paths_t, Vt, ctxb);
  gemm_bf16<true, false><<<dim3(D_ / 64, B_ * T_ / 64), 256, 0, stream>>>(
      (const void*)ctxb, Wot, (void*)out, B_ * T_, D_, D_);
}

// Round 4
// 135.687 us; speedup vs baseline: 2.5954x; 1.3211x over previous
//
#include <hip/hip_runtime.h>
#include <hip/hip_bf16.h>

#define B_ 2
#define T_ 1024
#define D_ 1024
#define H_ 8
#define DEPTH_ 5
#define DH_ 128

typedef short s16x8 __attribute__((ext_vector_type(8)));
typedef short s16x4 __attribute__((ext_vector_type(4)));
typedef float f32x4 __attribute__((ext_vector_type(4)));

__device__ inline short f2bf(float f) {
  __hip_bfloat16 h = __float2bfloat16(f);
  return *reinterpret_cast<short*>(&h);
}

// -------------------------------------------------------------------------
// Transpose + fp32->bf16 convert, dual-output (z=0: Wv->T0, z=1: Wo->T1).
// W[K][N] -> Wt[N][K] (bf16, k contiguous). 64x64 tiles.
// -------------------------------------------------------------------------
__global__ __launch_bounds__(256) void transpose_convert2(
    const float* __restrict__ W0, const float* __restrict__ W1,
    short* __restrict__ T0, short* __restrict__ T1, int K, int N) {
  const float* W = blockIdx.z ? W1 : W0;
  short* Wt = blockIdx.z ? T1 : T0;
  __shared__ float tile[64][65];
  int k0 = blockIdx.y * 64, n0 = blockIdx.x * 64;
  int tid = threadIdx.x;
#pragma unroll
  for (int i = 0; i < 4; ++i) {
    int idx = tid + i * 256;  // 0..1023
    int r = idx >> 4, c4 = (idx & 15) * 4;
    float4 v = *(const float4*)&W[(size_t)(k0 + r) * N + n0 + c4];
    tile[r][c4 + 0] = v.x;
    tile[r][c4 + 1] = v.y;
    tile[r][c4 + 2] = v.z;
    tile[r][c4 + 3] = v.w;
  }
  __syncthreads();
#pragma unroll
  for (int j = 0; j < 2; ++j) {
    int idx = tid + j * 256;  // 0..511
    int n = idx >> 3, k8 = (idx & 7) * 8;
    s16x8 outv;
#pragma unroll
    for (int jj = 0; jj < 8; ++jj) outv[jj] = f2bf(tile[k8 + jj][n]);
    *(s16x8*)&Wt[(size_t)(n0 + n) * K + k0 + k8] = outv;
  }
}

// -------------------------------------------------------------------------
// Wp[1024][40] -> rows 1024..1087 of WBt (bf16 [n][k]); rows >=40 zeroed.
// grid 32 x 256 threads, one s16x8 per thread.
// -------------------------------------------------------------------------
__global__ __launch_bounds__(256) void wp_transpose(
    const float* __restrict__ Wp, short* __restrict__ WBt) {
  int idx = blockIdx.x * 256 + threadIdx.x;  // 0..8191
  int row = idx >> 7;                         // 0..63
  int k8 = (idx & 127) * 8;
  s16x8 v;
  if (row < H_ * DEPTH_) {
#pragma unroll
    for (int j = 0; j < 8; ++j)
      v[j] = f2bf(Wp[(size_t)(k8 + j) * (H_ * DEPTH_) + row]);
  } else {
#pragma unroll
    for (int j = 0; j < 8; ++j) v[j] = 0;
  }
  *(s16x8*)&WBt[(size_t)(1024 + row) * D_ + k8] = v;
}

// -------------------------------------------------------------------------
// Fused x-GEMM: computes V = x@Wv (written bf16 transposed as
// Vt[(b*8+h)][dh][t]) AND paths = sigmoid(x@Wp+bp) (written fp32
// transposed (B,H,T,DEPTH)) from one pass over x.
// WBt[1088][1024] bf16: rows 0..1023 Wv^T, 1024..1063 Wp^T, rest zero.
// 64x64 block tile, BK=64, padded LDS stride 72, 4 waves, 2x2 MFMA/wave.
// mfma_f32_16x16x32_bf16; C/D: col=lane&15, row=(lane>>4)*4+reg.
// -------------------------------------------------------------------------
#define LS 72
__global__ __launch_bounds__(256) void gemm_x(
    const float* __restrict__ x, const short* __restrict__ WBt,
    const float* __restrict__ bp, short* __restrict__ Vt,
    float* __restrict__ paths_t) {
  __shared__ short As[64 * LS];
  __shared__ short Bs[64 * LS];
  int tid = threadIdx.x;
  int bm = blockIdx.y << 6, bn = blockIdx.x << 6;
  int wave = tid >> 6, lane = tid & 63;
  int wm = (wave >> 1) * 32, wn = (wave & 1) * 32;
  f32x4 acc[2][2] = {{{0.f, 0.f, 0.f, 0.f}, {0.f, 0.f, 0.f, 0.f}},
                     {{0.f, 0.f, 0.f, 0.f}, {0.f, 0.f, 0.f, 0.f}}};
  const int K = D_;

  for (int k0 = 0; k0 < K; k0 += 64) {
    s16x8 av[2], bv[2];
#pragma unroll
    for (int i = 0; i < 2; ++i) {
      int c = tid + i * 256;
      int row = c >> 3, ko = (c & 7) * 8;
      const float* p = &x[(size_t)(bm + row) * K + k0 + ko];
      float4 f0 = *(const float4*)p;
      float4 f1 = *(const float4*)(p + 4);
      av[i][0] = f2bf(f0.x); av[i][1] = f2bf(f0.y);
      av[i][2] = f2bf(f0.z); av[i][3] = f2bf(f0.w);
      av[i][4] = f2bf(f1.x); av[i][5] = f2bf(f1.y);
      av[i][6] = f2bf(f1.z); av[i][7] = f2bf(f1.w);
      bv[i] = *(const s16x8*)&WBt[(size_t)(bn + row) * K + k0 + ko];
    }
    __syncthreads();
#pragma unroll
    for (int i = 0; i < 2; ++i) {
      int c = tid + i * 256;
      int row = c >> 3, ko = (c & 7) * 8;
      *(s16x8*)&As[row * LS + ko] = av[i];
      *(s16x8*)&Bs[row * LS + ko] = bv[i];
    }
    __syncthreads();
#pragma unroll
    for (int ks = 0; ks < 2; ++ks) {
      int ko = ks * 32 + (lane >> 4) * 8;
      int fr = lane & 15;
      s16x8 a0 = *(const s16x8*)&As[(wm + fr) * LS + ko];
      s16x8 a1 = *(const s16x8*)&As[(wm + 16 + fr) * LS + ko];
      s16x8 b0 = *(const s16x8*)&Bs[(wn + fr) * LS + ko];
      s16x8 b1 = *(const s16x8*)&Bs[(wn + 16 + fr) * LS + ko];
      acc[0][0] = __builtin_amdgcn_mfma_f32_16x16x32_bf16(a0, b0, acc[0][0], 0, 0, 0);
      acc[0][1] = __builtin_amdgcn_mfma_f32_16x16x32_bf16(a0, b1, acc[0][1], 0, 0, 0);
      acc[1][0] = __builtin_amdgcn_mfma_f32_16x16x32_bf16(a1, b0, acc[1][0], 0, 0, 0);
      acc[1][1] = __builtin_amdgcn_mfma_f32_16x16x32_bf16(a1, b1, acc[1][1], 0, 0, 0);
    }
  }
  int col = lane & 15, rbase = (lane >> 4) * 4;
  if (bn < 1024) {
    // V epilogue: bf16, transposed [bh][dh][t]
#pragma unroll
    for (int mi = 0; mi < 2; ++mi)
#pragma unroll
      for (int ni = 0; ni < 2; ++ni) {
        int m = bm + wm + mi * 16 + rbase;  // t start (4 consecutive)
        int n = bn + wn + ni * 16 + col;    // dh col
        int b = m >> 10, t = m & (T_ - 1);
        int h = n >> 7, dh = n & (DH_ - 1);
        s16x4 v4;
#pragma unroll
        for (int r = 0; r < 4; ++r) v4[r] = f2bf(acc[mi][ni][r]);
        *(s16x4*)&Vt[((size_t)((b * H_ + h) * DH_ + dh)) * T_ + t] = v4;
      }
  } else {
    // paths epilogue: sigmoid(z + bp), fp32, (B,H,T,DEPTH)
#pragma unroll
    for (int ni = 0; ni < 2; ++ni) {
      int pn = wn + ni * 16 + col;  // 0..63
      if (pn < H_ * DEPTH_) {
        float bias = bp[pn];
        int h = pn / DEPTH_, d = pn % DEPTH_;
#pragma unroll
        for (int mi = 0; mi < 2; ++mi)
#pragma unroll
          for (int r = 0; r < 4; ++r) {
            int m = bm + wm + mi * 16 + rbase + r;
            int b = m >> 10, t = m & (T_ - 1);
            float p = 1.f / (1.f + __expf(-(acc[mi][ni][r] + bias)));
            paths_t[(((size_t)(b * H_ + h) * T_ + t) * DEPTH_) + d] = p;
          }
      }
    }
  }
}

// -------------------------------------------------------------------------
// MFMA bf16 GEMM (final projection): C = A[M][K] @ B, Bt[N][K] bf16.
// A is bf16. 64x64 tile, BK=64, fp32 output.
// -------------------------------------------------------------------------
__global__ __launch_bounds__(256) void gemm_out(
    const short* __restrict__ Ab, const short* __restrict__ Bt,
    float* __restrict__ C, int M, int N, int K) {
  __shared__ short As[64 * LS];
  __shared__ short Bs[64 * LS];
  int tid = threadIdx.x;
  int bm = blockIdx.y << 6, bn = blockIdx.x << 6;
  int wave = tid >> 6, lane = tid & 63;
  int wm = (wave >> 1) * 32, wn = (wave & 1) * 32;
  f32x4 acc[2][2] = {{{0.f, 0.f, 0.f, 0.f}, {0.f, 0.f, 0.f, 0.f}},
                     {{0.f, 0.f, 0.f, 0.f}, {0.f, 0.f, 0.f, 0.f}}};

  for (int k0 = 0; k0 < K; k0 += 64) {
    s16x8 av[2], bv[2];
#pragma unroll
    for (int i = 0; i < 2; ++i) {
      int c = tid + i * 256;
      int row = c >> 3, ko = (c & 7) * 8;
      av[i] = *(const s16x8*)&Ab[(size_t)(bm + row) * K + k0 + ko];
      bv[i] = *(const s16x8*)&Bt[(size_t)(bn + row) * K + k0 + ko];
    }
    __syncthreads();
#pragma unroll
    for (int i = 0; i < 2; ++i) {
      int c = tid + i * 256;
      int row = c >> 3, ko = (c & 7) * 8;
      *(s16x8*)&As[row * LS + ko] = av[i];
      *(s16x8*)&Bs[row * LS + ko] = bv[i];
    }
    __syncthreads();
#pragma unroll
    for (int ks = 0; ks < 2; ++ks) {
      int ko = ks * 32 + (lane >> 4) * 8;
      int fr = lane & 15;
      s16x8 a0 = *(const s16x8*)&As[(wm + fr) * LS + ko];
      s16x8 a1 = *(const s16x8*)&As[(wm + 16 + fr) * LS + ko];
      s16x8 b0 = *(const s16x8*)&Bs[(wn + fr) * LS + ko];
      s16x8 b1 = *(const s16x8*)&Bs[(wn + 16 + fr) * LS + ko];
      acc[0][0] = __builtin_amdgcn_mfma_f32_16x16x32_bf16(a0, b0, acc[0][0], 0, 0, 0);
      acc[0][1] = __builtin_amdgcn_mfma_f32_16x16x32_bf16(a0, b1, acc[0][1], 0, 0, 0);
      acc[1][0] = __builtin_amdgcn_mfma_f32_16x16x32_bf16(a1, b0, acc[1][0], 0, 0, 0);
      acc[1][1] = __builtin_amdgcn_mfma_f32_16x16x32_bf16(a1, b1, acc[1][1], 0, 0, 0);
    }
  }
  int col = lane & 15, rbase = (lane >> 4) * 4;
#pragma unroll
  for (int mi = 0; mi < 2; ++mi)
#pragma unroll
    for (int ni = 0; ni < 2; ++ni)
#pragma unroll
      for (int r = 0; r < 4; ++r)
        C[(size_t)(bm + wm + mi * 16 + rbase + r) * N + bn + wn + ni * 16 +
          col] = acc[mi][ni][r];
}

// -------------------------------------------------------------------------
// Fused causal p-adic attention, MFMA P·V (unchanged from round 3).
// -------------------------------------------------------------------------
#define QT 32
#define KT 64

__global__ __launch_bounds__(256) void attn_kernel(
    const float* __restrict__ paths_t, const short* __restrict__ Vt,
    short* __restrict__ ctxb) {
  int bh = blockIdx.y;  // 0..15
  int b = bh >> 3, h = bh & 7;
  int bx = blockIdx.x;  // 0..15
  int wave = threadIdx.x >> 6, lane = threadIdx.x & 63;

  __shared__ short Vs[DH_ * LS];  // [dh][k], stride 72
  __shared__ short Ss[QT * LS];   // [q][k],  stride 72
  __shared__ float lsum_s[QT];

  const float* pb = paths_t + (size_t)bh * T_ * DEPTH_;
  const short* vb = Vt + (size_t)bh * DH_ * T_;

  for (int half = 0; half < 2; ++half) {
    int qt = half ? (31 - bx) : bx;
    int q0 = qt * QT;
    int nkt = (q0 + QT - 1) / KT + 1;  // pair total = 17 always

    float pq[8][DEPTH_], mq[8][DEPTH_];
#pragma unroll
    for (int j = 0; j < 8; ++j) {
      const float* qr = pb + (size_t)(q0 + wave * 8 + j) * DEPTH_;
#pragma unroll
      for (int d = 0; d < DEPTH_; ++d) {
        pq[j][d] = qr[d];
        mq[j][d] = 1.f - pq[j][d];
      }
    }
    f32x4 acc[2][2] = {{{0.f, 0.f, 0.f, 0.f}, {0.f, 0.f, 0.f, 0.f}},
                       {{0.f, 0.f, 0.f, 0.f}, {0.f, 0.f, 0.f, 0.f}}};
    float part[8] = {};

    for (int kt = 0; kt < nkt; ++kt) {
      int k0 = kt * KT;
      __syncthreads();
#pragma unroll
      for (int i = 0; i < 4; ++i) {
        int c = threadIdx.x + i * 256;
        int dh = c >> 3, ko = (c & 7) * 8;
        *(s16x8*)&Vs[dh * LS + ko] =
            *(const s16x8*)&vb[(size_t)dh * T_ + k0 + ko];
      }
      int kg = k0 + lane;
      const float* kr = pb + (size_t)kg * DEPTH_;
      float pk[DEPTH_], mk[DEPTH_];
#pragma unroll
      for (int d = 0; d < DEPTH_; ++d) {
        pk[d] = kr[d];
        mk[d] = 1.f - pk[d];
      }
#pragma unroll
      for (int j = 0; j < 8; ++j) {
        int qg = q0 + wave * 8 + j;
        float a0 = fmaf(pq[j][0], pk[0], mq[j][0] * mk[0]);
        float a1 = fmaf(pq[j][1], pk[1], mq[j][1] * mk[1]);
        float a2 = fmaf(pq[j][2], pk[2], mq[j][2] * mk[2]);
        float a3 = fmaf(pq[j][3], pk[3], mq[j][3] * mk[3]);
        float a4 = fmaf(pq[j][4], pk[4], mq[j][4] * mk[4]);
        float t4 = 1.f + a4;
        float t3 = fmaf(a3, t4, 1.f);
        float t2 = fmaf(a2, t3, 1.f);
        float t1 = fmaf(a1, t2, 1.f);
        float s = a0 * t1;
        float w = (kg <= qg) ? __expf(s * 0.2f) : 0.f;
        part[j] += w;
        Ss[(wave * 8 + j) * LS + lane] = f2bf(w);
      }
      __syncthreads();
#pragma unroll
      for (int ks = 0; ks < 2; ++ks) {
        int ko = ks * 32 + (lane >> 4) * 8;
        int fr = lane & 15;
        s16x8 sa0 = *(const s16x8*)&Ss[fr * LS + ko];
        s16x8 sa1 = *(const s16x8*)&Ss[(16 + fr) * LS + ko];
        s16x8 vb0 = *(const s16x8*)&Vs[(wave * 32 + fr) * LS + ko];
        s16x8 vb1 = *(const s16x8*)&Vs[(wave * 32 + 16 + fr) * LS + ko];
        acc[0][0] = __builtin_amdgcn_mfma_f32_16x16x32_bf16(sa0, vb0, acc[0][0], 0, 0, 0);
        acc[0][1] = __builtin_amdgcn_mfma_f32_16x16x32_bf16(sa0, vb1, acc[0][1], 0, 0, 0);
        acc[1][0] = __builtin_amdgcn_mfma_f32_16x16x32_bf16(sa1, vb0, acc[1][0], 0, 0, 0);
        acc[1][1] = __builtin_amdgcn_mfma_f32_16x16x32_bf16(sa1, vb1, acc[1][1], 0, 0, 0);
      }
    }
#pragma unroll
    for (int j = 0; j < 8; ++j) {
      float s = part[j];
#pragma unroll
      for (int off = 32; off >= 1; off >>= 1) s += __shfl_xor(s, off, 64);
      if (lane == j) lsum_s[wave * 8 + j] = s;
    }
    __syncthreads();
    int col = lane & 15, rbase = (lane >> 4) * 4;
#pragma unroll
    for (int qt2 = 0; qt2 < 2; ++qt2)
#pragma unroll
      for (int ni = 0; ni < 2; ++ni)
#pragma unroll
        for (int r = 0; r < 4; ++r) {
          int ql = qt2 * 16 + rbase + r;
          int dh = wave * 32 + ni * 16 + col;
          float val = acc[qt2][ni][r] / lsum_s[ql];
          ctxb[(size_t)(b * T_ + q0 + ql) * D_ + h * DH_ + dh] = f2bf(val);
        }
  }
}

// -------------------------------------------------------------------------
extern "C" void kernel_launch(void* const* d_in, const int* in_sizes, int n_in,
                              void* d_out, int out_size, void* d_ws,
                              size_t ws_size, hipStream_t stream) {
  const float* x = (const float*)d_in[0];
  const float* Wp = (const float*)d_in[1];
  const float* bp = (const float*)d_in[2];
  const float* Wv = (const float*)d_in[3];
  const float* Wo = (const float*)d_in[4];
  float* out = (float*)d_out;

  char* ws = (char*)d_ws;
  float* paths_t = (float*)ws;                    //   327,680 B
  short* Vt = (short*)(ws + 327680);              // 4,194,304 B bf16 [bh][dh][t]
  short* WBt = (short*)(ws + 327680 + 4194304);   // 2,228,224 B bf16 [1088][1024]
  short* Wot = (short*)(ws + 327680 + 4194304 + 2228224);  // 2,097,152 B
  short* ctxb = (short*)(ws + 327680 + 4194304 + 2228224 + 2097152);  // 4 MB
  // total ~13.0 MB

  transpose_convert2<<<dim3(16, 16, 2), 256, 0, stream>>>(Wv, Wo, WBt, Wot,
                                                          D_, D_);
  wp_transpose<<<dim3(32), 256, 0, stream>>>(Wp, WBt);
  gemm_x<<<dim3(17, B_ * T_ / 64), 256, 0, stream>>>(x, WBt, bp, Vt, paths_t);
  attn_kernel<<<dim3(16, B_ * H_), 256, 0, stream>>>(paths_t, Vt, ctxb);
  gemm_out<<<dim3(D_ / 64, B_ * T_ / 64), 256, 0, stream>>>(ctxb, Wot, out,
                                                            B_ * T_, D_, D_);
}

// Round 5
// 128.861 us; speedup vs baseline: 2.7329x; 1.0530x over previous
//
#include <hip/hip_runtime.h>
#include <hip/hip_bf16.h>

#define B_ 2
#define T_ 1024
#define D_ 1024
#define H_ 8
#define DEPTH_ 5
#define DH_ 128

typedef short s16x8 __attribute__((ext_vector_type(8)));
typedef short s16x4 __attribute__((ext_vector_type(4)));
typedef float f32x4 __attribute__((ext_vector_type(4)));

__device__ inline short f2bf(float f) {
  __hip_bfloat16 h = __float2bfloat16(f);
  return *reinterpret_cast<short*>(&h);
}

// global -> LDS async copy, 16B per lane. LDS dest = base + lane*16.
typedef __attribute__((address_space(3))) unsigned int lds_u32_t;
typedef __attribute__((address_space(1))) unsigned int glb_u32_t;
__device__ __forceinline__ void glds16(const void* g, void* l) {
  __builtin_amdgcn_global_load_lds((const glb_u32_t*)g, (lds_u32_t*)l, 16, 0,
                                   0);
}

// -------------------------------------------------------------------------
// Prep (one launch, grid.z = 3):
//  z=0: Wv[K][N] -> WBt rows 0..1023   (bf16 [n][k])
//  z=1: Wo[K][N] -> Wot                (bf16 [n][k])
//  z=2: x fp32 -> xb bf16 (streaming); blocks 0..3 also scatter
//       Wp[1024][40] -> WBt rows 1024..1087 (rows >=40 zeroed).
// -------------------------------------------------------------------------
__global__ __launch_bounds__(256) void prep_kernel(
    const float* __restrict__ Wv, const float* __restrict__ Wo,
    const float* __restrict__ Wp, const float* __restrict__ x,
    short* __restrict__ WBt, short* __restrict__ Wot,
    short* __restrict__ xb) {
  int tid = threadIdx.x;
  if (blockIdx.z < 2) {
    const float* W = blockIdx.z ? Wo : Wv;
    short* Wt = blockIdx.z ? Wot : WBt;
    __shared__ float tile[64][65];
    int k0 = blockIdx.y * 64, n0 = blockIdx.x * 64;
#pragma unroll
    for (int i = 0; i < 4; ++i) {
      int idx = tid + i * 256;
      int r = idx >> 4, c4 = (idx & 15) * 4;
      float4 v = *(const float4*)&W[(size_t)(k0 + r) * D_ + n0 + c4];
      tile[r][c4 + 0] = v.x;
      tile[r][c4 + 1] = v.y;
      tile[r][c4 + 2] = v.z;
      tile[r][c4 + 3] = v.w;
    }
    __syncthreads();
#pragma unroll
    for (int j = 0; j < 2; ++j) {
      int idx = tid + j * 256;
      int n = idx >> 3, k8 = (idx & 7) * 8;
      s16x8 outv;
#pragma unroll
      for (int jj = 0; jj < 8; ++jj) outv[jj] = f2bf(tile[k8 + jj][n]);
      *(s16x8*)&Wt[(size_t)(n0 + n) * D_ + k0 + k8] = outv;
    }
  } else {
    int bid = blockIdx.y * 16 + blockIdx.x;  // 0..255
    // x -> bf16, 8192 elements per block
#pragma unroll
    for (int c = 0; c < 4; ++c) {
      size_t idx = (size_t)bid * 8192 + c * 2048 + tid * 8;
      float4 f0 = *(const float4*)&x[idx];
      float4 f1 = *(const float4*)&x[idx + 4];
      s16x8 v;
      v[0] = f2bf(f0.x); v[1] = f2bf(f0.y);
      v[2] = f2bf(f0.z); v[3] = f2bf(f0.w);
      v[4] = f2bf(f1.x); v[5] = f2bf(f1.y);
      v[6] = f2bf(f1.z); v[7] = f2bf(f1.w);
      *(s16x8*)&xb[idx] = v;
    }
    if (bid < 4) {  // Wp rows of WBt
#pragma unroll
      for (int it = 0; it < 8; ++it) {
        int item = bid * 2048 + it * 256 + tid;  // 0..8191
        int row = item >> 7, k8 = (item & 127) * 8;
        s16x8 v;
        if (row < H_ * DEPTH_) {
#pragma unroll
          for (int j = 0; j < 8; ++j)
            v[j] = f2bf(Wp[(size_t)(k8 + j) * (H_ * DEPTH_) + row]);
        } else {
#pragma unroll
          for (int j = 0; j < 8; ++j) v[j] = 0;
        }
        *(s16x8*)&WBt[(size_t)(1024 + row) * D_ + k8] = v;
      }
    }
  }
}

// -------------------------------------------------------------------------
// MFMA bf16 GEMM, 64x64 tile, BK=64, global_load_lds(16B) staging into
// unpadded LDS with XOR swizzle: physical slot p of row r holds logical
// 8-short colgroup p^(r&7)  ->  <=2-way bank aliasing on ds_read_b128.
// 4 waves (2x2), wave tile 32x32, mfma_f32_16x16x32_bf16.
// C/D: col=lane&15, row=(lane>>4)*4+reg.
// MODE 0: fp32 C[M][1024].  MODE 1: Vt bf16 [bh][dh][t] + paths epilogue.
// -------------------------------------------------------------------------
template <int MODE>
__global__ __launch_bounds__(256) void gemm64(
    const short* __restrict__ A, const short* __restrict__ Bt,
    float* __restrict__ Cf, const float* __restrict__ bp,
    short* __restrict__ Vt, float* __restrict__ paths_t) {
  __shared__ short As[64 * 64];
  __shared__ short Bs[64 * 64];
  const int K = D_;
  int tid = threadIdx.x;
  int bm = blockIdx.y << 6, bn = blockIdx.x << 6;
  int w = tid >> 6, lane = tid & 63;
  int wm = (w >> 1) * 32, wn = (w & 1) * 32;
  int g = lane >> 4, fr = lane & 15, frx = fr & 7;
  int srow = lane >> 3;                   // 0..7 within 8-row chunk
  int scol = ((lane & 7) ^ srow) * 8;     // swizzled source colgroup (shorts)
  f32x4 acc[2][2] = {{{0.f, 0.f, 0.f, 0.f}, {0.f, 0.f, 0.f, 0.f}},
                     {{0.f, 0.f, 0.f, 0.f}, {0.f, 0.f, 0.f, 0.f}}};

  const short* Ar0 = A + (size_t)(bm + w * 8 + srow) * K + scol;
  const short* Ar1 = A + (size_t)(bm + 32 + w * 8 + srow) * K + scol;
  const short* Br0 = Bt + (size_t)(bn + w * 8 + srow) * K + scol;
  const short* Br1 = Bt + (size_t)(bn + 32 + w * 8 + srow) * K + scol;
  short* lA0 = &As[(w * 8) * 64];
  short* lA1 = &As[(32 + w * 8) * 64];
  short* lB0 = &Bs[(w * 8) * 64];
  short* lB1 = &Bs[(32 + w * 8) * 64];

  for (int k0 = 0; k0 < K; k0 += 64) {
    __syncthreads();  // previous iteration's fragment readers done
    glds16(Ar0 + k0, lA0);
    glds16(Ar1 + k0, lA1);
    glds16(Br0 + k0, lB0);
    glds16(Br1 + k0, lB1);
    __syncthreads();  // drains vmcnt -> staged data visible
#pragma unroll
    for (int ks = 0; ks < 2; ++ks) {
      int sl = ((ks * 4 + g) ^ frx) * 8;
      s16x8 a0 = *(const s16x8*)&As[(wm + fr) * 64 + sl];
      s16x8 a1 = *(const s16x8*)&As[(wm + 16 + fr) * 64 + sl];
      s16x8 b0 = *(const s16x8*)&Bs[(wn + fr) * 64 + sl];
      s16x8 b1 = *(const s16x8*)&Bs[(wn + 16 + fr) * 64 + sl];
      acc[0][0] = __builtin_amdgcn_mfma_f32_16x16x32_bf16(a0, b0, acc[0][0], 0, 0, 0);
      acc[0][1] = __builtin_amdgcn_mfma_f32_16x16x32_bf16(a0, b1, acc[0][1], 0, 0, 0);
      acc[1][0] = __builtin_amdgcn_mfma_f32_16x16x32_bf16(a1, b0, acc[1][0], 0, 0, 0);
      acc[1][1] = __builtin_amdgcn_mfma_f32_16x16x32_bf16(a1, b1, acc[1][1], 0, 0, 0);
    }
  }
  int col = lane & 15, rbase = (lane >> 4) * 4;
  if (MODE == 0) {
#pragma unroll
    for (int mi = 0; mi < 2; ++mi)
#pragma unroll
      for (int ni = 0; ni < 2; ++ni)
#pragma unroll
        for (int r = 0; r < 4; ++r)
          Cf[(size_t)(bm + wm + mi * 16 + rbase + r) * D_ + bn + wn +
             ni * 16 + col] = acc[mi][ni][r];
  } else if (bn < 1024) {
    // V epilogue: bf16, transposed [bh][dh][t]
#pragma unroll
    for (int mi = 0; mi < 2; ++mi)
#pragma unroll
      for (int ni = 0; ni < 2; ++ni) {
        int m = bm + wm + mi * 16 + rbase;  // t start (4 consecutive)
        int n = bn + wn + ni * 16 + col;    // dh col
        int b = m >> 10, t = m & (T_ - 1);
        int h = n >> 7, dh = n & (DH_ - 1);
        s16x4 v4;
#pragma unroll
        for (int r = 0; r < 4; ++r) v4[r] = f2bf(acc[mi][ni][r]);
        *(s16x4*)&Vt[((size_t)((b * H_ + h) * DH_ + dh)) * T_ + t] = v4;
      }
  } else {
    // paths epilogue: sigmoid(z + bp), fp32, (B,H,T,DEPTH)
#pragma unroll
    for (int ni = 0; ni < 2; ++ni) {
      int pn = wn + ni * 16 + col;  // 0..63
      if (pn < H_ * DEPTH_) {
        float bias = bp[pn];
        int h = pn / DEPTH_, d = pn % DEPTH_;
#pragma unroll
        for (int mi = 0; mi < 2; ++mi)
#pragma unroll
          for (int r = 0; r < 4; ++r) {
            int m = bm + wm + mi * 16 + rbase + r;
            int b = m >> 10, t = m & (T_ - 1);
            float p = 1.f / (1.f + __expf(-(acc[mi][ni][r] + bias)));
            paths_t[(((size_t)(b * H_ + h) * T_ + t) * DEPTH_) + d] = p;
          }
      }
    }
  }
}

// -------------------------------------------------------------------------
// Fused causal p-adic attention, MFMA P.V.  512 threads / 8 waves:
// wave w owns dh strip [w*16, w*16+16) and sim rows q0+w*4..+3.
// Block handles q-tile pair (bx, 31-bx): exactly 17 k-tiles total.
// sim in [0,1] -> no max tracking; w = exp(sim/5), normalize at end.
// -------------------------------------------------------------------------
#define LS 72

__global__ __launch_bounds__(512) void attn_kernel(
    const float* __restrict__ paths_t, const short* __restrict__ Vt,
    short* __restrict__ ctxb) {
  int bh = blockIdx.y;  // 0..15
  int b = bh >> 3, h = bh & 7;
  int bx = blockIdx.x;  // 0..15
  int w = threadIdx.x >> 6, lane = threadIdx.x & 63;
  int g = lane >> 4, fr = lane & 15;

  __shared__ short Vs[DH_ * LS];  // [dh][k], stride 72
  __shared__ short Ss[32 * LS];   // [q][k],  stride 72
  __shared__ float lsum_s[32];

  const float* pb = paths_t + (size_t)bh * T_ * DEPTH_;
  const short* vb = Vt + (size_t)bh * DH_ * T_;

  for (int half = 0; half < 2; ++half) {
    int qt = half ? (31 - bx) : bx;
    int q0 = qt * 32;
    int nkt = q0 / 64 + 1;  // pair total = 17 always

    float pq[4][DEPTH_], mq[4][DEPTH_];
#pragma unroll
    for (int j = 0; j < 4; ++j) {
      const float* qr = pb + (size_t)(q0 + w * 4 + j) * DEPTH_;
#pragma unroll
      for (int d = 0; d < DEPTH_; ++d) {
        pq[j][d] = qr[d];
        mq[j][d] = 1.f - pq[j][d];
      }
    }
    f32x4 acc[2] = {{0.f, 0.f, 0.f, 0.f}, {0.f, 0.f, 0.f, 0.f}};
    float part[4] = {};

    for (int kt = 0; kt < nkt; ++kt) {
      int k0 = kt * 64;
      __syncthreads();  // prev MFMA readers / epilogue done
      // stage V tile: 128 dh rows x 64 k, bf16
#pragma unroll
      for (int i = 0; i < 2; ++i) {
        int c = threadIdx.x + i * 512;
        int dh = c >> 3, ko = (c & 7) * 8;
        *(s16x8*)&Vs[dh * LS + ko] =
            *(const s16x8*)&vb[(size_t)dh * T_ + k0 + ko];
      }
      // sim for k = k0+lane, q rows q0 + w*4 + j
      int kg = k0 + lane;
      const float* kr = pb + (size_t)kg * DEPTH_;
      float pk[DEPTH_], mk[DEPTH_];
#pragma unroll
      for (int d = 0; d < DEPTH_; ++d) {
        pk[d] = kr[d];
        mk[d] = 1.f - pk[d];
      }
#pragma unroll
      for (int j = 0; j < 4; ++j) {
        int qg = q0 + w * 4 + j;
        float a0 = fmaf(pq[j][0], pk[0], mq[j][0] * mk[0]);
        float a1 = fmaf(pq[j][1], pk[1], mq[j][1] * mk[1]);
        float a2 = fmaf(pq[j][2], pk[2], mq[j][2] * mk[2]);
        float a3 = fmaf(pq[j][3], pk[3], mq[j][3] * mk[3]);
        float a4 = fmaf(pq[j][4], pk[4], mq[j][4] * mk[4]);
        float t4 = 1.f + a4;
        float t3 = fmaf(a3, t4, 1.f);
        float t2 = fmaf(a2, t3, 1.f);
        float t1 = fmaf(a1, t2, 1.f);
        float s = a0 * t1;  // sum of cumprods
        float wv = (kg <= qg) ? __expf(s * 0.2f) : 0.f;
        part[j] += wv;
        Ss[(w * 4 + j) * LS + lane] = f2bf(wv);
      }
      __syncthreads();
      // P @ V via MFMA: wave covers dh [16*w, 16*w+16)
#pragma unroll
      for (int ks = 0; ks < 2; ++ks) {
        int ko = ks * 32 + g * 8;
        s16x8 sa0 = *(const s16x8*)&Ss[fr * LS + ko];
        s16x8 sa1 = *(const s16x8*)&Ss[(16 + fr) * LS + ko];
        s16x8 vv = *(const s16x8*)&Vs[(w * 16 + fr) * LS + ko];
        acc[0] = __builtin_amdgcn_mfma_f32_16x16x32_bf16(sa0, vv, acc[0], 0, 0, 0);
        acc[1] = __builtin_amdgcn_mfma_f32_16x16x32_bf16(sa1, vv, acc[1], 0, 0, 0);
      }
    }
    // reduce per-q row sums across the wave's 64 k-lanes
#pragma unroll
    for (int j = 0; j < 4; ++j) {
      float s = part[j];
#pragma unroll
      for (int off = 32; off >= 1; off >>= 1) s += __shfl_xor(s, off, 64);
      if (lane == j) lsum_s[w * 4 + j] = s;
    }
    __syncthreads();
    // epilogue: normalize, write bf16 ctx
    int col = lane & 15, rbase = g * 4;
#pragma unroll
    for (int qt2 = 0; qt2 < 2; ++qt2)
#pragma unroll
      for (int r = 0; r < 4; ++r) {
        int ql = qt2 * 16 + rbase + r;
        int dh = w * 16 + col;
        float val = acc[qt2][r] / lsum_s[ql];
        ctxb[(size_t)(b * T_ + q0 + ql) * D_ + h * DH_ + dh] = f2bf(val);
      }
  }
}

// -------------------------------------------------------------------------
extern "C" void kernel_launch(void* const* d_in, const int* in_sizes, int n_in,
                              void* d_out, int out_size, void* d_ws,
                              size_t ws_size, hipStream_t stream) {
  const float* x = (const float*)d_in[0];
  const float* Wp = (const float*)d_in[1];
  const float* bp = (const float*)d_in[2];
  const float* Wv = (const float*)d_in[3];
  const float* Wo = (const float*)d_in[4];
  float* out = (float*)d_out;

  char* ws = (char*)d_ws;
  float* paths_t = (float*)ws;                 //   327,680 B
  short* Vt = (short*)(ws + 327680);           // 4,194,304 B bf16 [bh][dh][t]
  short* WBt = (short*)(ws + 4521984);         // 2,228,224 B bf16 [1088][1024]
  short* Wot = (short*)(ws + 6750208);         // 2,097,152 B bf16 [1024][1024]
  short* ctxb = (short*)(ws + 8847360);        // 4,194,304 B bf16 [2048][1024]
  short* xb = (short*)(ws + 13041664);         // 4,194,304 B bf16 [2048][1024]
  // total ~17.2 MB

  prep_kernel<<<dim3(16, 16, 3), 256, 0, stream>>>(Wv, Wo, Wp, x, WBt, Wot,
                                                   xb);
  gemm64<1><<<dim3(17, 32), 256, 0, stream>>>(xb, WBt, nullptr, bp, Vt,
                                              paths_t);
  attn_kernel<<<dim3(16, B_ * H_), 512, 0, stream>>>(paths_t, Vt, ctxb);
  gemm64<0><<<dim3(16, 32), 256, 0, stream>>>(ctxb, Wot, out, nullptr,
                                              nullptr, nullptr);
}

// Round 6
// 127.953 us; speedup vs baseline: 2.7523x; 1.0071x over previous
//
#include <hip/hip_runtime.h>
#include <hip/hip_bf16.h>

#define B_ 2
#define T_ 1024
#define D_ 1024
#define H_ 8
#define DEPTH_ 5
#define DH_ 128

typedef short s16x8 __attribute__((ext_vector_type(8)));
typedef short s16x4 __attribute__((ext_vector_type(4)));
typedef float f32x4 __attribute__((ext_vector_type(4)));

__device__ inline short f2bf(float f) {
  __hip_bfloat16 h = __float2bfloat16(f);
  return *reinterpret_cast<short*>(&h);
}

// global -> LDS async copy, 16B per lane. LDS dest = wave-uniform base + lane*16.
typedef __attribute__((address_space(3))) unsigned int lds_u32_t;
typedef __attribute__((address_space(1))) unsigned int glb_u32_t;
__device__ __forceinline__ void glds16(const void* g, void* l) {
  __builtin_amdgcn_global_load_lds((const glb_u32_t*)g, (lds_u32_t*)l, 16, 0,
                                   0);
}

// -------------------------------------------------------------------------
// Prep (one launch, grid.z = 3):
//  z=0: Wv[K][N] -> WBt rows 0..1023   (bf16 [n][k])
//  z=1: Wo[K][N] -> Wot                (bf16 [n][k])
//  z=2: x fp32 -> xb bf16 (streaming); blocks 0..3 also scatter
//       Wp[1024][40] -> WBt rows 1024..1087 (rows >=40 zeroed).
// -------------------------------------------------------------------------
__global__ __launch_bounds__(256) void prep_kernel(
    const float* __restrict__ Wv, const float* __restrict__ Wo,
    const float* __restrict__ Wp, const float* __restrict__ x,
    short* __restrict__ WBt, short* __restrict__ Wot,
    short* __restrict__ xb) {
  int tid = threadIdx.x;
  if (blockIdx.z < 2) {
    const float* W = blockIdx.z ? Wo : Wv;
    short* Wt = blockIdx.z ? Wot : WBt;
    __shared__ float tile[64][65];
    int k0 = blockIdx.y * 64, n0 = blockIdx.x * 64;
#pragma unroll
    for (int i = 0; i < 4; ++i) {
      int idx = tid + i * 256;
      int r = idx >> 4, c4 = (idx & 15) * 4;
      float4 v = *(const float4*)&W[(size_t)(k0 + r) * D_ + n0 + c4];
      tile[r][c4 + 0] = v.x;
      tile[r][c4 + 1] = v.y;
      tile[r][c4 + 2] = v.z;
      tile[r][c4 + 3] = v.w;
    }
    __syncthreads();
#pragma unroll
    for (int j = 0; j < 2; ++j) {
      int idx = tid + j * 256;
      int n = idx >> 3, k8 = (idx & 7) * 8;
      s16x8 outv;
#pragma unroll
      for (int jj = 0; jj < 8; ++jj) outv[jj] = f2bf(tile[k8 + jj][n]);
      *(s16x8*)&Wt[(size_t)(n0 + n) * D_ + k0 + k8] = outv;
    }
  } else {
    int bid = blockIdx.y * 16 + blockIdx.x;  // 0..255
#pragma unroll
    for (int c = 0; c < 4; ++c) {
      size_t idx = (size_t)bid * 8192 + c * 2048 + tid * 8;
      float4 f0 = *(const float4*)&x[idx];
      float4 f1 = *(const float4*)&x[idx + 4];
      s16x8 v;
      v[0] = f2bf(f0.x); v[1] = f2bf(f0.y);
      v[2] = f2bf(f0.z); v[3] = f2bf(f0.w);
      v[4] = f2bf(f1.x); v[5] = f2bf(f1.y);
      v[6] = f2bf(f1.z); v[7] = f2bf(f1.w);
      *(s16x8*)&xb[idx] = v;
    }
    if (bid < 4) {  // Wp rows of WBt
#pragma unroll
      for (int it = 0; it < 8; ++it) {
        int item = bid * 2048 + it * 256 + tid;  // 0..8191
        int row = item >> 7, k8 = (item & 127) * 8;
        s16x8 v;
        if (row < H_ * DEPTH_) {
#pragma unroll
          for (int j = 0; j < 8; ++j)
            v[j] = f2bf(Wp[(size_t)(k8 + j) * (H_ * DEPTH_) + row]);
        } else {
#pragma unroll
          for (int j = 0; j < 8; ++j) v[j] = 0;
        }
        *(s16x8*)&WBt[(size_t)(1024 + row) * D_ + k8] = v;
      }
    }
  }
}

// -------------------------------------------------------------------------
// MFMA bf16 GEMM, 64x64 tile, BK=128 (8 K-iters, half the barrier drains).
// glds16 staging into unpadded LDS with XOR swizzle: logical colgroup g of
// row r lives at physical g^(r&15) (swizzle applied on the SOURCE address —
// glds only constrains the dest). Fragment ds_read_b128 lands uniform over
// banks. 4 waves (2x2), wave tile 32x32, 16 MFMA/wave/iter.
// C/D: col=lane&15, row=(lane>>4)*4+reg.
// MODE 0: fp32 C[M][1024].  MODE 1: Vt bf16 [bh][dh][t] + paths epilogue.
// -------------------------------------------------------------------------
template <int MODE>
__global__ __launch_bounds__(256) void gemm128(
    const short* __restrict__ A, const short* __restrict__ Bt,
    float* __restrict__ Cf, const float* __restrict__ bp,
    short* __restrict__ Vt, float* __restrict__ paths_t) {
  __shared__ short As[64 * 128];  // 16 KB
  __shared__ short Bs[64 * 128];  // 16 KB
  const int K = D_;
  int tid = threadIdx.x;
  int bm = blockIdx.y << 6, bn = blockIdx.x << 6;
  int w = tid >> 6, lane = tid & 63;
  int wm = (w >> 1) * 32, wn = (w & 1) * 32;
  int g = lane >> 4, fr = lane & 15;
  f32x4 acc[2][2] = {{{0.f, 0.f, 0.f, 0.f}, {0.f, 0.f, 0.f, 0.f}},
                     {{0.f, 0.f, 0.f, 0.f}, {0.f, 0.f, 0.f, 0.f}}};

  // staging: wave w owns rows [w*16, w*16+16); glds i covers rows w*16+i*4..+3
  int r4 = lane >> 4;   // row within 4-row chunk
  int cg = lane & 15;   // dest physical colgroup
  const short* Asrc[4];
  const short* Bsrc[4];
  short* Adst[4];
  short* Bdst[4];
#pragma unroll
  for (int i = 0; i < 4; ++i) {
    int row = w * 16 + i * 4 + r4;
    int scol = (cg ^ (row & 15)) * 8;  // source colgroup (XOR swizzle)
    Asrc[i] = A + (size_t)(bm + row) * K + scol;
    Bsrc[i] = Bt + (size_t)(bn + row) * K + scol;
    Adst[i] = &As[(w * 16 + i * 4) * 128];
    Bdst[i] = &Bs[(w * 16 + i * 4) * 128];
  }

  for (int k0 = 0; k0 < K; k0 += 128) {
    __syncthreads();  // previous iteration's fragment readers done
#pragma unroll
    for (int i = 0; i < 4; ++i) {
      glds16(Asrc[i] + k0, Adst[i]);
      glds16(Bsrc[i] + k0, Bdst[i]);
    }
    __syncthreads();  // drains vmcnt -> staged data visible
#pragma unroll
    for (int ks = 0; ks < 4; ++ks) {
      int p = (((ks * 4 + g) ^ fr)) * 8;  // physical slot (rows used have row&15==fr)
      s16x8 a0 = *(const s16x8*)&As[(wm + fr) * 128 + p];
      s16x8 a1 = *(const s16x8*)&As[(wm + 16 + fr) * 128 + p];
      s16x8 b0 = *(const s16x8*)&Bs[(wn + fr) * 128 + p];
      s16x8 b1 = *(const s16x8*)&Bs[(wn + 16 + fr) * 128 + p];
      acc[0][0] = __builtin_amdgcn_mfma_f32_16x16x32_bf16(a0, b0, acc[0][0], 0, 0, 0);
      acc[0][1] = __builtin_amdgcn_mfma_f32_16x16x32_bf16(a0, b1, acc[0][1], 0, 0, 0);
      acc[1][0] = __builtin_amdgcn_mfma_f32_16x16x32_bf16(a1, b0, acc[1][0], 0, 0, 0);
      acc[1][1] = __builtin_amdgcn_mfma_f32_16x16x32_bf16(a1, b1, acc[1][1], 0, 0, 0);
    }
  }
  int col = lane & 15, rbase = (lane >> 4) * 4;
  if (MODE == 0) {
#pragma unroll
    for (int mi = 0; mi < 2; ++mi)
#pragma unroll
      for (int ni = 0; ni < 2; ++ni)
#pragma unroll
        for (int r = 0; r < 4; ++r)
          Cf[(size_t)(bm + wm + mi * 16 + rbase + r) * D_ + bn + wn +
             ni * 16 + col] = acc[mi][ni][r];
  } else if (bn < 1024) {
    // V epilogue: bf16, transposed [bh][dh][t]
#pragma unroll
    for (int mi = 0; mi < 2; ++mi)
#pragma unroll
      for (int ni = 0; ni < 2; ++ni) {
        int m = bm + wm + mi * 16 + rbase;  // t start (4 consecutive)
        int n = bn + wn + ni * 16 + col;    // dh col
        int b = m >> 10, t = m & (T_ - 1);
        int h = n >> 7, dh = n & (DH_ - 1);
        s16x4 v4;
#pragma unroll
        for (int r = 0; r < 4; ++r) v4[r] = f2bf(acc[mi][ni][r]);
        *(s16x4*)&Vt[((size_t)((b * H_ + h) * DH_ + dh)) * T_ + t] = v4;
      }
  } else {
    // paths epilogue: sigmoid(z + bp), fp32, (B,H,T,DEPTH)
#pragma unroll
    for (int ni = 0; ni < 2; ++ni) {
      int pn = wn + ni * 16 + col;  // 0..63
      if (pn < H_ * DEPTH_) {
        float bias = bp[pn];
        int h = pn / DEPTH_, d = pn % DEPTH_;
#pragma unroll
        for (int mi = 0; mi < 2; ++mi)
#pragma unroll
          for (int r = 0; r < 4; ++r) {
            int m = bm + wm + mi * 16 + rbase + r;
            int b = m >> 10, t = m & (T_ - 1);
            float p = 1.f / (1.f + __expf(-(acc[mi][ni][r] + bias)));
            paths_t[(((size_t)(b * H_ + h) * T_ + t) * DEPTH_) + d] = p;
          }
      }
    }
  }
}

// -------------------------------------------------------------------------
// Fused causal p-adic attention, MFMA P.V.  512 threads / 8 waves.
// KT=128: 9 k-tiles per block-pair (qt/4 + (31-qt)/4 + 2 == 9 for all qt).
// Wave w owns dh strip [w*16, w*16+16) and sim rows q0+w*4..+3; each lane
// computes sim for 2 k-columns (k0+lane, k0+64+lane).
// sim in [0,1] -> no max tracking; w = exp(sim/5), normalize at end.
// -------------------------------------------------------------------------
#define LS2 136

__global__ __launch_bounds__(512) void attn_kernel(
    const float* __restrict__ paths_t, const short* __restrict__ Vt,
    short* __restrict__ ctxb) {
  int bh = blockIdx.y;  // 0..15
  int b = bh >> 3, h = bh & 7;
  int bx = blockIdx.x;  // 0..15
  int w = threadIdx.x >> 6, lane = threadIdx.x & 63;
  int g = lane >> 4, fr = lane & 15;

  __shared__ short Vs[DH_ * LS2];  // [dh][k], stride 136, ~34 KB
  __shared__ short Ss[32 * LS2];   // [q][k],  stride 136, ~8.5 KB
  __shared__ float lsum_s[32];

  const float* pb = paths_t + (size_t)bh * T_ * DEPTH_;
  const short* vb = Vt + (size_t)bh * DH_ * T_;

  for (int half = 0; half < 2; ++half) {
    int qt = half ? (31 - bx) : bx;
    int q0 = qt * 32;
    int nkt = (qt >> 2) + 1;  // k-tiles of 128; pair total = 9 always

    float pq[4][DEPTH_], mq[4][DEPTH_];
#pragma unroll
    for (int j = 0; j < 4; ++j) {
      const float* qr = pb + (size_t)(q0 + w * 4 + j) * DEPTH_;
#pragma unroll
      for (int d = 0; d < DEPTH_; ++d) {
        pq[j][d] = qr[d];
        mq[j][d] = 1.f - pq[j][d];
      }
    }
    f32x4 acc[2] = {{0.f, 0.f, 0.f, 0.f}, {0.f, 0.f, 0.f, 0.f}};
    float part[4] = {};

    for (int kt = 0; kt < nkt; ++kt) {
      int k0 = kt * 128;
      __syncthreads();  // prev MFMA readers / epilogue done
      // stage V tile: 128 dh rows x 128 k, bf16 (32 KB)
#pragma unroll
      for (int i = 0; i < 4; ++i) {
        int c = threadIdx.x + i * 512;
        int dh = c >> 4, ko = (c & 15) * 8;
        *(s16x8*)&Vs[dh * LS2 + ko] =
            *(const s16x8*)&vb[(size_t)dh * T_ + k0 + ko];
      }
      // sim for kA = k0+lane, kB = k0+64+lane
      int kA = k0 + lane, kB = k0 + 64 + lane;
      const float* krA = pb + (size_t)kA * DEPTH_;
      const float* krB = pb + (size_t)kB * DEPTH_;
      float pkA[DEPTH_], mkA[DEPTH_], pkB[DEPTH_], mkB[DEPTH_];
#pragma unroll
      for (int d = 0; d < DEPTH_; ++d) {
        pkA[d] = krA[d]; mkA[d] = 1.f - pkA[d];
        pkB[d] = krB[d]; mkB[d] = 1.f - pkB[d];
      }
#pragma unroll
      for (int j = 0; j < 4; ++j) {
        int qg = q0 + w * 4 + j;
        // k = kA
        {
          float a0 = fmaf(pq[j][0], pkA[0], mq[j][0] * mkA[0]);
          float a1 = fmaf(pq[j][1], pkA[1], mq[j][1] * mkA[1]);
          float a2 = fmaf(pq[j][2], pkA[2], mq[j][2] * mkA[2]);
          float a3 = fmaf(pq[j][3], pkA[3], mq[j][3] * mkA[3]);
          float a4 = fmaf(pq[j][4], pkA[4], mq[j][4] * mkA[4]);
          float t4 = 1.f + a4;
          float t3 = fmaf(a3, t4, 1.f);
          float t2 = fmaf(a2, t3, 1.f);
          float t1 = fmaf(a1, t2, 1.f);
          float s = a0 * t1;
          float wv = (kA <= qg) ? __expf(s * 0.2f) : 0.f;
          part[j] += wv;
          Ss[(w * 4 + j) * LS2 + lane] = f2bf(wv);
        }
        // k = kB
        {
          float a0 = fmaf(pq[j][0], pkB[0], mq[j][0] * mkB[0]);
          float a1 = fmaf(pq[j][1], pkB[1], mq[j][1] * mkB[1]);
          float a2 = fmaf(pq[j][2], pkB[2], mq[j][2] * mkB[2]);
          float a3 = fmaf(pq[j][3], pkB[3], mq[j][3] * mkB[3]);
          float a4 = fmaf(pq[j][4], pkB[4], mq[j][4] * mkB[4]);
          float t4 = 1.f + a4;
          float t3 = fmaf(a3, t4, 1.f);
          float t2 = fmaf(a2, t3, 1.f);
          float t1 = fmaf(a1, t2, 1.f);
          float s = a0 * t1;
          float wv = (kB <= qg) ? __expf(s * 0.2f) : 0.f;
          part[j] += wv;
          Ss[(w * 4 + j) * LS2 + 64 + lane] = f2bf(wv);
        }
      }
      __syncthreads();
      // P @ V via MFMA: wave covers dh [16*w, 16*w+16); 4 ks steps of k32
#pragma unroll
      for (int ks = 0; ks < 4; ++ks) {
        int ko = ks * 32 + g * 8;
        s16x8 sa0 = *(const s16x8*)&Ss[fr * LS2 + ko];
        s16x8 sa1 = *(const s16x8*)&Ss[(16 + fr) * LS2 + ko];
        s16x8 vv = *(const s16x8*)&Vs[(w * 16 + fr) * LS2 + ko];
        acc[0] = __builtin_amdgcn_mfma_f32_16x16x32_bf16(sa0, vv, acc[0], 0, 0, 0);
        acc[1] = __builtin_amdgcn_mfma_f32_16x16x32_bf16(sa1, vv, acc[1], 0, 0, 0);
      }
    }
    // reduce per-q row sums across the wave's 64 lanes (each lane holds 2 k)
#pragma unroll
    for (int j = 0; j < 4; ++j) {
      float s = part[j];
#pragma unroll
      for (int off = 32; off >= 1; off >>= 1) s += __shfl_xor(s, off, 64);
      if (lane == j) lsum_s[w * 4 + j] = s;
    }
    __syncthreads();
    // epilogue: normalize, write bf16 ctx
    int col = lane & 15, rbase = g * 4;
#pragma unroll
    for (int qt2 = 0; qt2 < 2; ++qt2)
#pragma unroll
      for (int r = 0; r < 4; ++r) {
        int ql = qt2 * 16 + rbase + r;
        int dh = w * 16 + col;
        float val = acc[qt2][r] / lsum_s[ql];
        ctxb[(size_t)(b * T_ + q0 + ql) * D_ + h * DH_ + dh] = f2bf(val);
      }
  }
}

// -------------------------------------------------------------------------
extern "C" void kernel_launch(void* const* d_in, const int* in_sizes, int n_in,
                              void* d_out, int out_size, void* d_ws,
                              size_t ws_size, hipStream_t stream) {
  const float* x = (const float*)d_in[0];
  const float* Wp = (const float*)d_in[1];
  const float* bp = (const float*)d_in[2];
  const float* Wv = (const float*)d_in[3];
  const float* Wo = (const float*)d_in[4];
  float* out = (float*)d_out;

  char* ws = (char*)d_ws;
  float* paths_t = (float*)ws;                 //   327,680 B
  short* Vt = (short*)(ws + 327680);           // 4,194,304 B bf16 [bh][dh][t]
  short* WBt = (short*)(ws + 4521984);         // 2,228,224 B bf16 [1088][1024]
  short* Wot = (short*)(ws + 6750208);         // 2,097,152 B bf16 [1024][1024]
  short* ctxb = (short*)(ws + 8847360);        // 4,194,304 B bf16 [2048][1024]
  short* xb = (short*)(ws + 13041664);         // 4,194,304 B bf16 [2048][1024]
  // total ~17.2 MB

  prep_kernel<<<dim3(16, 16, 3), 256, 0, stream>>>(Wv, Wo, Wp, x, WBt, Wot,
                                                   xb);
  gemm128<1><<<dim3(17, 32), 256, 0, stream>>>(xb, WBt, nullptr, bp, Vt,
                                               paths_t);
  attn_kernel<<<dim3(16, B_ * H_), 512, 0, stream>>>(paths_t, Vt, ctxb);
  gemm128<0><<<dim3(16, 32), 256, 0, stream>>>(ctxb, Wot, out, nullptr,
                                               nullptr, nullptr);
}